// Round 12
// baseline (195.213 us; speedup 1.0000x reference)
//
#include <hip/hip_runtime.h>
#include <hip/hip_bf16.h>
#include <stdint.h>

#define DIM    256
#define NH     4
#define HD     64
#define BATCH  4
#define SEQ    4096
#define NTOK   (BATCH*SEQ)

typedef __bf16    bf16_t;
typedef __bf16    bf16x4 __attribute__((ext_vector_type(4)));
typedef _Float16  f16_t;
typedef _Float16  f16x8  __attribute__((ext_vector_type(8)));
typedef _Float16  f16x4  __attribute__((ext_vector_type(4)));
typedef float     f32x4  __attribute__((ext_vector_type(4)));
typedef float     f32x16 __attribute__((ext_vector_type(16)));
typedef unsigned short u16x8 __attribute__((ext_vector_type(8)));
typedef unsigned int   u32;
typedef u32 u32x2 __attribute__((ext_vector_type(2)));
typedef u32 u32x4 __attribute__((ext_vector_type(4)));

#define MFMA_F16    __builtin_amdgcn_mfma_f32_16x16x32_f16
#define MFMA32_F16  __builtin_amdgcn_mfma_f32_32x32x16_f16

// HEAD_DIM^-0.5 * log2(e): fold softmax scale + exp->exp2 into q at projection time
#define QSCALE 0.18033688011112042f

// ws layout in f16 element units (oattA lives at WS_XA; only attn writes it now)
#define WS_XA    ((size_t)0)          /* attn output in tiled A-layout */
#define WS_Q     ((size_t)4194304)
#define WS_K     ((size_t)8388608)
#define WS_VT    ((size_t)12582912)
#define WS_W     ((size_t)16777216)   /* 4 x 65536 tiled: wqT,wkT,wvT,woT */
#define WS_BO    ((size_t)17039360)   /* float[256] */
#define WS_OATT  WS_XA

// Tiled fragment layout: elem (row, k) -> ((row>>4)*32 + (k>>3))*128 + (row&15)*8 + (k&7)
__device__ __forceinline__ size_t tiled_idx(int row, int k) {
  return ((size_t)(row >> 4) * 32 + (k >> 3)) * 128 + (row & 15) * 8 + (k & 7);
}

// ---------------------------------------------------------------------------
// In-block dtype detect (0 = bf16 inputs, 1 = fp32 inputs)
__device__ __forceinline__ int detect_mode(const uint32_t* wq_u32) {
  uint32_t word = wq_u32[(threadIdx.x & 63) * 431 + 17];   // < 32768 dwords
  uint32_t b = (word >> 8) & 0x7fu;
  unsigned long long m = __ballot(b >= 0x38u && b <= 0x3fu);
  return (__popcll(m) >= 32) ? 0 : 1;
}

__device__ __forceinline__ f16x8 cvt_chunk(const void* src, size_t elem, int mode) {
  f16x8 r;
  if (mode) {
    const float* s = (const float*)src + elem;
    f32x4 f0 = *(const f32x4*)(s);
    f32x4 f1 = *(const f32x4*)(s + 4);
    #pragma unroll
    for (int j = 0; j < 4; ++j) { r[j] = (f16_t)f0[j]; r[j + 4] = (f16_t)f1[j]; }
  } else {
    u16x8 v = *(const u16x8*)((const unsigned short*)src + elem);
    #pragma unroll
    for (int j = 0; j < 8; ++j) r[j] = (f16_t)__uint_as_float(((unsigned)v[j]) << 16);
  }
  return r;
}

// pack two f32 -> one dword of 2 f16 (v_cvt_pkrtz_f16_f32)
__device__ __forceinline__ u32 pkh(float a, float b) {
  auto h = __builtin_amdgcn_cvt_pkrtz(a, b);   // __fp16 ext_vector_type(2)
  return __builtin_bit_cast(u32, h);
}

// (x,y) -> (concat(x.lo,y.lo), concat(x.hi,y.hi))  [lane halves]
__device__ __forceinline__ void swap32(u32& x, u32& y) {
#if __has_builtin(__builtin_amdgcn_permlane32_swap)
  u32x2 r = __builtin_amdgcn_permlane32_swap(x, y, false, false);
  x = r[0]; y = r[1];
#else
  u32 xp = __shfl_xor((int)x, 32), yp = __shfl_xor((int)y, 32);
  const bool h = (threadIdx.x & 32) != 0;
  u32 nx = h ? yp : x;
  u32 ny = h ? y  : xp;
  x = nx; y = ny;
#endif
}

// ---------------------------------------------------------------------------
// cvt_w: weights (blocks 0..127) -> fp16 tiled; bias (block 128) -> f32.
// Round-21: the x pass (2048 blocks + 25MB round-trip) moved into proj,
// which converts x inline while building fragments.
__global__ __launch_bounds__(256) void cvt_w_kernel(
    const void* __restrict__ wq, const void* __restrict__ wk,
    const void* __restrict__ wv, const void* __restrict__ wo,
    const void* __restrict__ bo,
    f16_t* __restrict__ wT, float* __restrict__ bof) {
  __shared__ int s_mode;
  if (threadIdx.x < 64) {
    int m = detect_mode((const uint32_t*)wq);
    if (threadIdx.x == 0) s_mode = m;
  }
  __syncthreads();
  const int mode = s_mode;
  const int bid = blockIdx.x;

  if (bid < 128) {                      // weights: 4 x 8192 chunks
    int idx = bid * 256 + (int)threadIdx.x;
    int which = idx >> 13, local = idx & 8191;
    const void* src = (which == 0) ? wq : (which == 1) ? wk : (which == 2) ? wv : wo;
    int n = local >> 5, kc = local & 31;
    f16x8 r = cvt_chunk(src, (size_t)n * DIM + kc * 8, mode);
    *(f16x8*)(wT + (size_t)which * 65536 + tiled_idx(n, kc * 8)) = r;
  } else {
    int i = threadIdx.x;
    bof[i] = mode ? ((const float*)bo)[i] : (float)((const bf16_t*)bo)[i];
  }
}

// ---------------------------------------------------------------------------
// Fused single-pass QKV projection (round-21): x fragments converted INLINE
// from the raw input (cvt_chunk; B-frag elem = x[tok][k] by the R20-verified
// A==B frag-formula identity) — the separate x-conversion pass is gone.
// One kernel, grid (256,4): each x fragment feeds all three weights.
// Output image layouts byte-identical to the R20-passing code.
__global__ __launch_bounds__(256) void proj_fused_kernel(
    const void* __restrict__ x, const f16_t* __restrict__ wT,
    f16_t* __restrict__ q, f16_t* __restrict__ kk, f16_t* __restrict__ vt,
    const void* __restrict__ wq_raw) {
  __shared__ int s_mode;
  if (threadIdx.x < 64) {
    int m = detect_mode((const uint32_t*)wq_raw);
    if (threadIdx.x == 0) s_mode = m;
  }
  __syncthreads();
  const int mode = s_mode;

  const int lane = threadIdx.x & 63;
  const int wvi  = threadIdx.x >> 6;
  const int c    = lane & 15;
  const int g    = lane >> 4;

  const int m0 = blockIdx.y * 64 + wvi * 16;   // out-dim rows (q,k) / vd cols (v)
  const int n0 = blockIdx.x * 64;              // token tile

  const f16_t* aq = wT + (size_t)(m0 >> 4) * 4096 + c * 8;              // wq
  const f16_t* ak = wT + 65536 + (size_t)(m0 >> 4) * 4096 + c * 8;      // wk
  const f16_t* av = wT + 131072 + (size_t)(m0 >> 4) * 4096 + c * 8;     // wv

  f32x4 accq[4] = {}, acck[4] = {}, accv[4] = {};
  #pragma unroll
  for (int ks = 0; ks < 8; ++ks) {
    const int kc = (ks * 4 + g) * 128;
    const int k0 = (ks * 4 + g) * 8;
    f16x8 xf[4];
    #pragma unroll
    for (int nt = 0; nt < 4; ++nt)
      xf[nt] = cvt_chunk(x, (size_t)(n0 + nt * 16 + c) * DIM + k0, mode);
    f16x8 wqf = *(const f16x8*)(aq + kc);
    f16x8 wkf = *(const f16x8*)(ak + kc);
    f16x8 wvf = *(const f16x8*)(av + kc);
    #pragma unroll
    for (int nt = 0; nt < 4; ++nt) {
      accq[nt] = MFMA_F16(wqf, xf[nt], accq[nt], 0, 0, 0);  // C[d rows][tok cols]
      acck[nt] = MFMA_F16(wkf, xf[nt], acck[nt], 0, 0, 0);  // C[d rows][tok cols]
      accv[nt] = MFMA_F16(xf[nt], wvf, accv[nt], 0, 0, 0);  // C[tok rows][vd cols]
    }
  }

  // ---- q epilogue: rows = out-dim (4 consecutive d), cols = tokens ----
  const int nb = m0 + g * 4;
  const int hq = nb >> 6, d0 = nb & 63;
  #pragma unroll
  for (int nt = 0; nt < 4; ++nt) {
    const int tok = n0 + nt * 16 + c;
    const int b = tok >> 12, s = tok & 4095;
    f16x4 ov = { (f16_t)(accq[nt][0] * QSCALE), (f16_t)(accq[nt][1] * QSCALE),
                 (f16_t)(accq[nt][2] * QSCALE), (f16_t)(accq[nt][3] * QSCALE) };
    *(f16x4*)(q + (size_t)((b * NH + hq) * SEQ + s) * HD + d0) = ov;
  }

  // ---- K frag-image epilogue: [bh][kt64][h2][sg][hi2][row(32)][8] ----
  {
    const int sg = d0 >> 4, hi2 = (d0 >> 3) & 1, j0 = d0 & 7;
    #pragma unroll
    for (int nt = 0; nt < 4; ++nt) {
      const int tok = n0 + nt * 16 + c;
      const int b = tok >> 12, s = tok & 4095;
      const int kt = s >> 6, h2 = (s >> 5) & 1, row = s & 31;
      f16x4 ov = { (f16_t)acck[nt][0], (f16_t)acck[nt][1],
                   (f16_t)acck[nt][2], (f16_t)acck[nt][3] };
      *(f16x4*)(kk + (size_t)(b * NH + hq) * (SEQ * HD) + (size_t)kt * 4096 +
                h2 * 2048 + sg * 512 + hi2 * 256 + row * 8 + j0) = ov;
    }
  }

  // ---- V frag-image epilogue: rows = tokens (4 consecutive jv), cols = vd ----
  #pragma unroll
  for (int nt = 0; nt < 4; ++nt) {
    const int tok0 = n0 + nt * 16 + g * 4;       // 4 consecutive tokens
    const int b = tok0 >> 12, s0 = tok0 & 4095;
    const int kt = s0 >> 6, kin0 = s0 & 63;
    const int h2 = kin0 >> 5, kb = (kin0 >> 4) & 1, hiv = (kin0 >> 3) & 1, jv0 = kin0 & 7;
    const int vd = m0 + c;
    const int h = vd >> 6, d = vd & 63;
    f16x4 ov = { (f16_t)accv[nt][0], (f16_t)accv[nt][1],
                 (f16_t)accv[nt][2], (f16_t)accv[nt][3] };
    *(f16x4*)(vt + (size_t)(b * NH + h) * (SEQ * HD) + (size_t)kt * 4096 +
              h2 * 2048 + (d >> 5) * 1024 + kb * 512 + hiv * 256 +
              (d & 31) * 8 + jv0) = ov;
  }
}

// ---------------------------------------------------------------------------
// Flash attention — R8-verified frag-streaming kernel (77.6 µs, 0 bank
// conflicts), kept verbatim. 2 waves/SIMD is the hard cap: the wave holds
// ~180 unified regs (116 VGPR + 64 AGPR acc); HW occupancy steps at
// 64/128/256 regs, so >128 rounds to a 256-slot ⇒ exactly 2 waves/SIMD.
__global__ __launch_bounds__(256, 2) void attn_kernel(
    const f16_t* __restrict__ q, const f16_t* __restrict__ kimg,
    const f16_t* __restrict__ vimg, f16_t* __restrict__ o) {
  __shared__ __align__(16) f16_t smem[16896];   // epilogue: 32KB red + 1KB lred

  const int tid = threadIdx.x;
  const int l   = tid & 63;
  const int w   = tid >> 6;
  const int wq_ = w & 1;           // q half: 64 queries
  const int wk_ = w >> 1;          // k half of each 64-key tile: 32 keys
  const int ql  = l & 31;
  const int hi  = l >> 5;
  const int bh  = blockIdx.x;      // XCD-locality: id%8 == bh%8
  const int q0  = blockIdx.y * 128;

  // Q B-frags (32x32x16: col=l&31, k=hi*8+j): qf[qt][s] over d = s*16+hi*8..+8
  const f16_t* qb = q + ((size_t)bh * SEQ + q0 + wq_ * 64 + ql) * HD + hi * 8;
  f16x8 qf[2][4];
  #pragma unroll
  for (int qt = 0; qt < 2; ++qt)
    #pragma unroll
    for (int s = 0; s < 4; ++s)
      qf[qt][s] = *(const f16x8*)(qb + (size_t)qt * 32 * HD + s * 16);

  // per-wave fragment base pointers into the frag-images (f16 units)
  const f16_t* kW = kimg + (size_t)bh * (SEQ * HD) + wk_ * 2048 + l * 8;
  const f16_t* vW = vimg + (size_t)bh * (SEQ * HD) + wk_ * 2048 + l * 8;

  f32x16 acc[2][2] = {};           // [dt][qt]: O^T[d=dt*32+crow][q=qt*32+ql]
  float lsum[2] = {0.f, 0.f};

  f16x8 kfA[4], vfA[2][2], kfB[4], vfB[2][2];

  // load tile 0 into A
  #pragma unroll
  for (int s = 0; s < 4; ++s) kfA[s] = *(const f16x8*)(kW + s * 512);
  #pragma unroll
  for (int dt = 0; dt < 2; ++dt)
    #pragma unroll
    for (int kb = 0; kb < 2; ++kb)
      vfA[dt][kb] = *(const f16x8*)(vW + dt * 1024 + kb * 512);

  auto body = [&](f16x8 (&kf)[4], f16x8 (&vf)[2][2],
                  f16x8 (&kfn)[4], f16x8 (&vfn)[2][2], int kt) {
    if (kt < SEQ / 64 - 1) {                 // prefetch tile kt+1 -> other regs
      const f16_t* kP = kW + (size_t)(kt + 1) * 4096;
      const f16_t* vP = vW + (size_t)(kt + 1) * 4096;
      #pragma unroll
      for (int s = 0; s < 4; ++s) kfn[s] = *(const f16x8*)(kP + s * 512);
      #pragma unroll
      for (int dt = 0; dt < 2; ++dt)
        #pragma unroll
        for (int kb = 0; kb < 2; ++kb)
          vfn[dt][kb] = *(const f16x8*)(vP + dt * 1024 + kb * 512);
    }
    #pragma unroll
    for (int qt = 0; qt < 2; ++qt) {
      f32x16 st = {};
      #pragma unroll
      for (int s = 0; s < 4; ++s) st = MFMA32_F16(kf[s], qf[qt][s], st, 0, 0, 0);
      float p[16];
      #pragma unroll
      for (int r = 0; r < 16; ++r) p[r] = __builtin_amdgcn_exp2f(st[r]);
      float ls = 0.f;
      #pragma unroll
      for (int r = 0; r < 16; r += 4) ls += (p[r] + p[r + 1]) + (p[r + 2] + p[r + 3]);
      lsum[qt] += ls;
      f16x8 pf0, pf1;
      {
        u32 d0 = pkh(p[0], p[1]), d1 = pkh(p[2], p[3]);
        u32 d2 = pkh(p[4], p[5]), d3 = pkh(p[6], p[7]);
        swap32(d0, d2); swap32(d1, d3);
        u32x4 fd; fd[0] = d0; fd[1] = d1; fd[2] = d2; fd[3] = d3;
        pf0 = __builtin_bit_cast(f16x8, fd);
      }
      {
        u32 d0 = pkh(p[8], p[9]),  d1 = pkh(p[10], p[11]);
        u32 d2 = pkh(p[12], p[13]), d3 = pkh(p[14], p[15]);
        swap32(d0, d2); swap32(d1, d3);
        u32x4 fd; fd[0] = d0; fd[1] = d1; fd[2] = d2; fd[3] = d3;
        pf1 = __builtin_bit_cast(f16x8, fd);
      }
      #pragma unroll
      for (int dt = 0; dt < 2; ++dt) {
        f32x16 a = acc[dt][qt];
        a = MFMA32_F16(vf[dt][0], pf0, a, 0, 0, 0);
        a = MFMA32_F16(vf[dt][1], pf1, a, 0, 0, 0);
        acc[dt][qt] = a;
      }
    }
  };

  for (int kt = 0; kt < SEQ / 64; kt += 2) {
    body(kfA, vfA, kfB, vfB, kt);
    body(kfB, vfB, kfA, vfA, kt + 1);
  }

  // ---- reductions: l across hi halves + wk pair; O^T 2-way via LDS ----
  float* lred = (float*)(smem + 16384);          // byte 32768: 256 floats
  #pragma unroll
  for (int qt = 0; qt < 2; ++qt) {
    lsum[qt] += __shfl_xor(lsum[qt], 32);
    if (hi == 0) lred[w * 64 + qt * 32 + ql] = lsum[qt];
  }
  float* red = (float*)smem;                     // 32KB staging region
  if (wk_ == 1) {
    #pragma unroll
    for (int t = 0; t < 4; ++t) {
      f32x16 a = acc[t >> 1][t & 1];
      #pragma unroll
      for (int qd = 0; qd < 4; ++qd) {
        f32x4 v = { a[qd * 4], a[qd * 4 + 1], a[qd * 4 + 2], a[qd * 4 + 3] };
        *(f32x4*)(red + wq_ * 4096 + (t * 4 + qd) * 256 + l * 4) = v;
      }
    }
  }
  __syncthreads();
  if (wk_ == 0) {
    float inv[2];
    #pragma unroll
    for (int qt = 0; qt < 2; ++qt)
      inv[qt] = 1.0f / (lred[w * 64 + qt * 32 + ql] + lred[(w + 2) * 64 + qt * 32 + ql]);

    const int b = bh >> 2, h = bh & 3;
    #pragma unroll
    for (int dt = 0; dt < 2; ++dt)
      #pragma unroll
      for (int qt = 0; qt < 2; ++qt) {
        const int t = dt * 2 + qt;
        f32x16 a = acc[dt][qt];
        const int tokg = b * SEQ + q0 + wq_ * 64 + qt * 32 + ql;
        const size_t rowbase = (size_t)(tokg >> 4) * 4096 + (tokg & 15) * 8 + hi * 4;
        #pragma unroll
        for (int qd = 0; qd < 4; ++qd) {
          f32x4 v = *(const f32x4*)(red + wq_ * 4096 + (t * 4 + qd) * 256 + l * 4);
          // d = dt*32 + 8*qd + 4*hi + m ; kk_col = h*64 + d (tiled A-layout)
          f16x4 ov = { (f16_t)((a[qd * 4 + 0] + v[0]) * inv[qt]),
                       (f16_t)((a[qd * 4 + 1] + v[1]) * inv[qt]),
                       (f16_t)((a[qd * 4 + 2] + v[2]) * inv[qt]),
                       (f16_t)((a[qd * 4 + 3] + v[3]) * inv[qt]) };
          *(f16x4*)(o + rowbase + (size_t)(h * 8 + dt * 4 + qd) * 128) = ov;
        }
      }
  }
}

// ---------------------------------------------------------------------------
// output projection: C rows = out-dim (a = woT frag) so each thread holds
// 4 consecutive n of one token -> float4 / bf16x4 stores.
__global__ __launch_bounds__(256) void out_proj_kernel(
    const f16_t* __restrict__ aA, const f16_t* __restrict__ wT,
    const float* __restrict__ bo, void* __restrict__ outv,
    const void* __restrict__ wq_raw) {
  __shared__ int s_mode;
  if (threadIdx.x < 64) {
    int m = detect_mode((const uint32_t*)wq_raw);
    if (threadIdx.x == 0) s_mode = m;
  }
  __syncthreads();
  const int mode = s_mode;

  const int lane = threadIdx.x & 63;
  const int wv   = threadIdx.x >> 6;
  const int c    = lane & 15;
  const int g    = lane >> 4;
  const int m0   = blockIdx.y * 64 + wv * 16;    // out-dim rows (4 y-blocks)
  const int n0   = blockIdx.x * 64;              // token cols (256 x-blocks)

  const f16_t* abase = wT + (size_t)(m0 >> 4) * 4096 + c * 8;
  const f16_t* bbase = aA + (size_t)(n0 >> 4) * 4096 + c * 8;
  f32x4 acc[4] = {};

  #pragma unroll
  for (int ks = 0; ks < 8; ++ks) {
    const int kc = (ks * 4 + g) * 128;
    f16x8 aw = *(const f16x8*)(abase + kc);
    #pragma unroll
    for (int nt = 0; nt < 4; ++nt) {
      f16x8 ba = *(const f16x8*)(bbase + (size_t)nt * 4096 + kc);
      acc[nt] = MFMA_F16(aw, ba, acc[nt], 0, 0, 0);
    }
  }

  const int nb = m0 + g * 4;                     // 4 consecutive out-dims
  const f32x4 bias = *(const f32x4*)(bo + nb);
  #pragma unroll
  for (int nt = 0; nt < 4; ++nt) {
    const int tok = n0 + nt * 16 + c;
    const size_t idx = (size_t)tok * DIM + nb;
    f32x4 v = { acc[nt][0] + bias[0], acc[nt][1] + bias[1],
                acc[nt][2] + bias[2], acc[nt][3] + bias[3] };
    if (mode) {
      *(f32x4*)((float*)outv + idx) = v;
    } else {
      bf16x4 ov = { (bf16_t)v[0], (bf16_t)v[1], (bf16_t)v[2], (bf16_t)v[3] };
      *(bf16x4*)((bf16_t*)outv + idx) = ov;
    }
  }
}

// ---------------------------------------------------------------------------
extern "C" void kernel_launch(void* const* d_in, const int* in_sizes, int n_in,
                              void* d_out, int out_size, void* d_ws, size_t ws_size,
                              hipStream_t stream) {
  (void)in_sizes; (void)n_in; (void)out_size; (void)ws_size;
  const void* x  = d_in[0];
  const void* wq = d_in[1];
  const void* wk = d_in[2];
  const void* wv = d_in[3];
  const void* wo = d_in[4];
  const void* bo = d_in[5];

  f16_t* ws    = (f16_t*)d_ws;
  f16_t* q     = ws + WS_Q;
  f16_t* kk    = ws + WS_K;
  f16_t* vt    = ws + WS_VT;
  f16_t* wT    = ws + WS_W;
  f16_t* woT   = ws + WS_W + 196608;
  float* bof   = (float*)(ws + WS_BO);
  f16_t* oattA = ws + WS_OATT;

  cvt_w_kernel     <<<dim3(129),       256, 0, stream>>>(wq, wk, wv, wo, bo,
                                                         wT, bof);
  proj_fused_kernel<<<dim3(256, 4),    256, 0, stream>>>(x, wT, q, kk, vt, wq);
  attn_kernel      <<<dim3(16, 32),    256, 0, stream>>>(q, kk, vt, oattA);
  out_proj_kernel  <<<dim3(256, 4),    256, 0, stream>>>(oattA, woT, bof, d_out, wq);
}

// Round 13
// 185.823 us; speedup vs baseline: 1.0505x; 1.0505x over previous
//
#include <hip/hip_runtime.h>
#include <hip/hip_bf16.h>
#include <stdint.h>

#define DIM    256
#define NH     4
#define HD     64
#define BATCH  4
#define SEQ    4096
#define NTOK   (BATCH*SEQ)

typedef __bf16    bf16_t;
typedef __bf16    bf16x4 __attribute__((ext_vector_type(4)));
typedef _Float16  f16_t;
typedef _Float16  f16x8  __attribute__((ext_vector_type(8)));
typedef _Float16  f16x4  __attribute__((ext_vector_type(4)));
typedef float     f32x4  __attribute__((ext_vector_type(4)));
typedef float     f32x16 __attribute__((ext_vector_type(16)));
typedef unsigned short u16x8 __attribute__((ext_vector_type(8)));
typedef unsigned int   u32;
typedef u32 u32x2 __attribute__((ext_vector_type(2)));
typedef u32 u32x4 __attribute__((ext_vector_type(4)));

#define MFMA_F16    __builtin_amdgcn_mfma_f32_16x16x32_f16
#define MFMA32_F16  __builtin_amdgcn_mfma_f32_32x32x16_f16

// HEAD_DIM^-0.5 * log2(e): fold softmax scale + exp->exp2 into q at projection time
#define QSCALE 0.18033688011112042f

// ws layout in f16 element units (oattA aliases xA — x dead after projections)
#define WS_XA    ((size_t)0)          /* x in tiled A-layout, 16384x256 */
#define WS_Q     ((size_t)4194304)
#define WS_K     ((size_t)8388608)
#define WS_VT    ((size_t)12582912)
#define WS_W     ((size_t)16777216)   /* 4 x 65536 tiled: wqT,wkT,wvT,woT */
#define WS_BO    ((size_t)17039360)   /* float[256] */
#define WS_OATT  WS_XA

// Tiled fragment layout: elem (row, k) -> ((row>>4)*32 + (k>>3))*128 + (row&15)*8 + (k&7)
__device__ __forceinline__ size_t tiled_idx(int row, int k) {
  return ((size_t)(row >> 4) * 32 + (k >> 3)) * 128 + (row & 15) * 8 + (k & 7);
}

// ---------------------------------------------------------------------------
// In-block dtype detect (0 = bf16 inputs, 1 = fp32 inputs)
__device__ __forceinline__ int detect_mode(const uint32_t* wq_u32) {
  uint32_t word = wq_u32[(threadIdx.x & 63) * 431 + 17];   // < 32768 dwords
  uint32_t b = (word >> 8) & 0x7fu;
  unsigned long long m = __ballot(b >= 0x38u && b <= 0x3fu);
  return (__popcll(m) >= 32) ? 0 : 1;
}

__device__ __forceinline__ f16x8 cvt_chunk(const void* src, size_t elem, int mode) {
  f16x8 r;
  if (mode) {
    const float* s = (const float*)src + elem;
    f32x4 f0 = *(const f32x4*)(s);
    f32x4 f1 = *(const f32x4*)(s + 4);
    #pragma unroll
    for (int j = 0; j < 4; ++j) { r[j] = (f16_t)f0[j]; r[j + 4] = (f16_t)f1[j]; }
  } else {
    u16x8 v = *(const u16x8*)((const unsigned short*)src + elem);
    #pragma unroll
    for (int j = 0; j < 8; ++j) r[j] = (f16_t)__uint_as_float(((unsigned)v[j]) << 16);
  }
  return r;
}

// pack two f32 -> one dword of 2 f16 (v_cvt_pkrtz_f16_f32)
__device__ __forceinline__ u32 pkh(float a, float b) {
  auto h = __builtin_amdgcn_cvt_pkrtz(a, b);   // __fp16 ext_vector_type(2)
  return __builtin_bit_cast(u32, h);
}

// (x,y) -> (concat(x.lo,y.lo), concat(x.hi,y.hi))  [lane halves]
__device__ __forceinline__ void swap32(u32& x, u32& y) {
#if __has_builtin(__builtin_amdgcn_permlane32_swap)
  u32x2 r = __builtin_amdgcn_permlane32_swap(x, y, false, false);
  x = r[0]; y = r[1];
#else
  u32 xp = __shfl_xor((int)x, 32), yp = __shfl_xor((int)y, 32);
  const bool h = (threadIdx.x & 32) != 0;
  u32 nx = h ? yp : x;
  u32 ny = h ? y  : xp;
  x = nx; y = ny;
#endif
}

// ---------------------------------------------------------------------------
// cvt_all: x (blocks 0..2047) and 4 weights (2048..2175) -> fp16 in the TILED
// fragment layout; bias (block 2176) -> f32. One 8-elem chunk per thread.
// (R12 lesson: inline x-conversion in proj makes the x reads uncoalesced at
// 512B lane stride + 4x y-redundant — the separate coalesced pass is faster.)
__global__ __launch_bounds__(256) void cvt_all_kernel(
    const void* __restrict__ x,
    const void* __restrict__ wq, const void* __restrict__ wk,
    const void* __restrict__ wv, const void* __restrict__ wo,
    const void* __restrict__ bo,
    f16_t* __restrict__ xA, f16_t* __restrict__ wT,
    float* __restrict__ bof) {
  __shared__ int s_mode;
  if (threadIdx.x < 64) {
    int m = detect_mode((const uint32_t*)wq);
    if (threadIdx.x == 0) s_mode = m;
  }
  __syncthreads();
  const int mode = s_mode;
  const int bid = blockIdx.x;

  if (bid < 2048) {                     // x: 524288 chunks
    int idx = bid * 256 + (int)threadIdx.x;
    int tok = idx >> 5, kc = idx & 31;
    f16x8 r = cvt_chunk(x, (size_t)tok * DIM + kc * 8, mode);
    *(f16x8*)(xA + tiled_idx(tok, kc * 8)) = r;
  } else if (bid < 2176) {              // weights: 4 x 8192 chunks
    int idx = (bid - 2048) * 256 + (int)threadIdx.x;
    int which = idx >> 13, local = idx & 8191;
    const void* src = (which == 0) ? wq : (which == 1) ? wk : (which == 2) ? wv : wo;
    int n = local >> 5, kc = local & 31;
    f16x8 r = cvt_chunk(src, (size_t)n * DIM + kc * 8, mode);
    *(f16x8*)(wT + (size_t)which * 65536 + tiled_idx(n, kc * 8)) = r;
  } else {
    int i = threadIdx.x;
    bof[i] = mode ? ((const float*)bo)[i] : (float)((const bf16_t*)bo)[i];
  }
}

// ---------------------------------------------------------------------------
// Fused single-pass QKV projection (R20-verified, 174.5 µs config). One
// kernel, grid (256,4): each xA fragment is loaded ONCE and feeds all three
// weights — the tiled layout's A-frag and B-frag load formulas are identical,
// so xf[nt] serves as B-operand for Q/K (C rows = out-dim -> vectorized
// q/K-image stores) and as A-operand for V (C rows = token -> vectorized
// V-image stores).
__global__ __launch_bounds__(256) void proj_fused_kernel(
    const f16_t* __restrict__ xA, const f16_t* __restrict__ wT,
    f16_t* __restrict__ q, f16_t* __restrict__ kk, f16_t* __restrict__ vt) {
  const int lane = threadIdx.x & 63;
  const int wvi  = threadIdx.x >> 6;
  const int c    = lane & 15;
  const int g    = lane >> 4;

  const int m0 = blockIdx.y * 64 + wvi * 16;   // out-dim rows (q,k) / vd cols (v)
  const int n0 = blockIdx.x * 64;              // token tile

  const f16_t* aq = wT + (size_t)(m0 >> 4) * 4096 + c * 8;              // wq
  const f16_t* ak = wT + 65536 + (size_t)(m0 >> 4) * 4096 + c * 8;      // wk
  const f16_t* av = wT + 131072 + (size_t)(m0 >> 4) * 4096 + c * 8;     // wv
  const f16_t* bx = xA + (size_t)(n0 >> 4) * 4096 + c * 8;

  f32x4 accq[4] = {}, acck[4] = {}, accv[4] = {};
  #pragma unroll
  for (int ks = 0; ks < 8; ++ks) {
    const int kc = (ks * 4 + g) * 128;
    f16x8 xf[4];
    #pragma unroll
    for (int nt = 0; nt < 4; ++nt)
      xf[nt] = *(const f16x8*)(bx + (size_t)nt * 4096 + kc);
    f16x8 wqf = *(const f16x8*)(aq + kc);
    f16x8 wkf = *(const f16x8*)(ak + kc);
    f16x8 wvf = *(const f16x8*)(av + kc);
    #pragma unroll
    for (int nt = 0; nt < 4; ++nt) {
      accq[nt] = MFMA_F16(wqf, xf[nt], accq[nt], 0, 0, 0);  // C[d rows][tok cols]
      acck[nt] = MFMA_F16(wkf, xf[nt], acck[nt], 0, 0, 0);  // C[d rows][tok cols]
      accv[nt] = MFMA_F16(xf[nt], wvf, accv[nt], 0, 0, 0);  // C[tok rows][vd cols]
    }
  }

  // ---- q epilogue: rows = out-dim (4 consecutive d), cols = tokens ----
  const int nb = m0 + g * 4;
  const int hq = nb >> 6, d0 = nb & 63;
  #pragma unroll
  for (int nt = 0; nt < 4; ++nt) {
    const int tok = n0 + nt * 16 + c;
    const int b = tok >> 12, s = tok & 4095;
    f16x4 ov = { (f16_t)(accq[nt][0] * QSCALE), (f16_t)(accq[nt][1] * QSCALE),
                 (f16_t)(accq[nt][2] * QSCALE), (f16_t)(accq[nt][3] * QSCALE) };
    *(f16x4*)(q + (size_t)((b * NH + hq) * SEQ + s) * HD + d0) = ov;
  }

  // ---- K frag-image epilogue: [bh][kt64][h2][sg][hi2][row(32)][8] ----
  {
    const int sg = d0 >> 4, hi2 = (d0 >> 3) & 1, j0 = d0 & 7;
    #pragma unroll
    for (int nt = 0; nt < 4; ++nt) {
      const int tok = n0 + nt * 16 + c;
      const int b = tok >> 12, s = tok & 4095;
      const int kt = s >> 6, h2 = (s >> 5) & 1, row = s & 31;
      f16x4 ov = { (f16_t)acck[nt][0], (f16_t)acck[nt][1],
                   (f16_t)acck[nt][2], (f16_t)acck[nt][3] };
      *(f16x4*)(kk + (size_t)(b * NH + hq) * (SEQ * HD) + (size_t)kt * 4096 +
                h2 * 2048 + sg * 512 + hi2 * 256 + row * 8 + j0) = ov;
    }
  }

  // ---- V frag-image epilogue: rows = tokens (4 consecutive jv), cols = vd ----
  #pragma unroll
  for (int nt = 0; nt < 4; ++nt) {
    const int tok0 = n0 + nt * 16 + g * 4;       // 4 consecutive tokens
    const int b = tok0 >> 12, s0 = tok0 & 4095;
    const int kt = s0 >> 6, kin0 = s0 & 63;
    const int h2 = kin0 >> 5, kb = (kin0 >> 4) & 1, hiv = (kin0 >> 3) & 1, jv0 = kin0 & 7;
    const int vd = m0 + c;
    const int h = vd >> 6, d = vd & 63;
    f16x4 ov = { (f16_t)accv[nt][0], (f16_t)accv[nt][1],
                 (f16_t)accv[nt][2], (f16_t)accv[nt][3] };
    *(f16x4*)(vt + (size_t)(b * NH + h) * (SEQ * HD) + (size_t)kt * 4096 +
              h2 * 2048 + (d >> 5) * 1024 + kb * 512 + hiv * 256 +
              (d & 31) * 8 + jv0) = ov;
  }
}

// ---------------------------------------------------------------------------
// Flash attention — R8-verified frag-streaming kernel (77.6 µs, 0 bank
// conflicts) + T5 s_setprio around the MFMA clusters (free-running waves at
// different phases = the regime where setprio paid +4-7% in m191).
// 2 waves/SIMD is the hard cap: the wave holds ~180 unified regs (116 VGPR +
// 64 AGPR acc); HW occupancy steps at 64/128/256 regs ⇒ exactly 2 waves/SIMD.
__global__ __launch_bounds__(256, 2) void attn_kernel(
    const f16_t* __restrict__ q, const f16_t* __restrict__ kimg,
    const f16_t* __restrict__ vimg, f16_t* __restrict__ o) {
  __shared__ __align__(16) f16_t smem[16896];   // epilogue: 32KB red + 1KB lred

  const int tid = threadIdx.x;
  const int l   = tid & 63;
  const int w   = tid >> 6;
  const int wq_ = w & 1;           // q half: 64 queries
  const int wk_ = w >> 1;          // k half of each 64-key tile: 32 keys
  const int ql  = l & 31;
  const int hi  = l >> 5;
  const int bh  = blockIdx.x;      // XCD-locality: id%8 == bh%8
  const int q0  = blockIdx.y * 128;

  // Q B-frags (32x32x16: col=l&31, k=hi*8+j): qf[qt][s] over d = s*16+hi*8..+8
  const f16_t* qb = q + ((size_t)bh * SEQ + q0 + wq_ * 64 + ql) * HD + hi * 8;
  f16x8 qf[2][4];
  #pragma unroll
  for (int qt = 0; qt < 2; ++qt)
    #pragma unroll
    for (int s = 0; s < 4; ++s)
      qf[qt][s] = *(const f16x8*)(qb + (size_t)qt * 32 * HD + s * 16);

  // per-wave fragment base pointers into the frag-images (f16 units)
  const f16_t* kW = kimg + (size_t)bh * (SEQ * HD) + wk_ * 2048 + l * 8;
  const f16_t* vW = vimg + (size_t)bh * (SEQ * HD) + wk_ * 2048 + l * 8;

  f32x16 acc[2][2] = {};           // [dt][qt]: O^T[d=dt*32+crow][q=qt*32+ql]
  float lsum[2] = {0.f, 0.f};

  f16x8 kfA[4], vfA[2][2], kfB[4], vfB[2][2];

  // load tile 0 into A
  #pragma unroll
  for (int s = 0; s < 4; ++s) kfA[s] = *(const f16x8*)(kW + s * 512);
  #pragma unroll
  for (int dt = 0; dt < 2; ++dt)
    #pragma unroll
    for (int kb = 0; kb < 2; ++kb)
      vfA[dt][kb] = *(const f16x8*)(vW + dt * 1024 + kb * 512);

  auto body = [&](f16x8 (&kf)[4], f16x8 (&vf)[2][2],
                  f16x8 (&kfn)[4], f16x8 (&vfn)[2][2], int kt) {
    if (kt < SEQ / 64 - 1) {                 // prefetch tile kt+1 -> other regs
      const f16_t* kP = kW + (size_t)(kt + 1) * 4096;
      const f16_t* vP = vW + (size_t)(kt + 1) * 4096;
      #pragma unroll
      for (int s = 0; s < 4; ++s) kfn[s] = *(const f16x8*)(kP + s * 512);
      #pragma unroll
      for (int dt = 0; dt < 2; ++dt)
        #pragma unroll
        for (int kb = 0; kb < 2; ++kb)
          vfn[dt][kb] = *(const f16x8*)(vP + dt * 1024 + kb * 512);
    }
    #pragma unroll
    for (int qt = 0; qt < 2; ++qt) {
      __builtin_amdgcn_s_setprio(1);
      f32x16 st = {};
      #pragma unroll
      for (int s = 0; s < 4; ++s) st = MFMA32_F16(kf[s], qf[qt][s], st, 0, 0, 0);
      __builtin_amdgcn_s_setprio(0);
      float p[16];
      #pragma unroll
      for (int r = 0; r < 16; ++r) p[r] = __builtin_amdgcn_exp2f(st[r]);
      float ls = 0.f;
      #pragma unroll
      for (int r = 0; r < 16; r += 4) ls += (p[r] + p[r + 1]) + (p[r + 2] + p[r + 3]);
      lsum[qt] += ls;
      f16x8 pf0, pf1;
      {
        u32 d0 = pkh(p[0], p[1]), d1 = pkh(p[2], p[3]);
        u32 d2 = pkh(p[4], p[5]), d3 = pkh(p[6], p[7]);
        swap32(d0, d2); swap32(d1, d3);
        u32x4 fd; fd[0] = d0; fd[1] = d1; fd[2] = d2; fd[3] = d3;
        pf0 = __builtin_bit_cast(f16x8, fd);
      }
      {
        u32 d0 = pkh(p[8], p[9]),  d1 = pkh(p[10], p[11]);
        u32 d2 = pkh(p[12], p[13]), d3 = pkh(p[14], p[15]);
        swap32(d0, d2); swap32(d1, d3);
        u32x4 fd; fd[0] = d0; fd[1] = d1; fd[2] = d2; fd[3] = d3;
        pf1 = __builtin_bit_cast(f16x8, fd);
      }
      __builtin_amdgcn_s_setprio(1);
      #pragma unroll
      for (int dt = 0; dt < 2; ++dt) {
        f32x16 a = acc[dt][qt];
        a = MFMA32_F16(vf[dt][0], pf0, a, 0, 0, 0);
        a = MFMA32_F16(vf[dt][1], pf1, a, 0, 0, 0);
        acc[dt][qt] = a;
      }
      __builtin_amdgcn_s_setprio(0);
    }
  };

  for (int kt = 0; kt < SEQ / 64; kt += 2) {
    body(kfA, vfA, kfB, vfB, kt);
    body(kfB, vfB, kfA, vfA, kt + 1);
  }

  // ---- reductions: l across hi halves + wk pair; O^T 2-way via LDS ----
  float* lred = (float*)(smem + 16384);          // byte 32768: 256 floats
  #pragma unroll
  for (int qt = 0; qt < 2; ++qt) {
    lsum[qt] += __shfl_xor(lsum[qt], 32);
    if (hi == 0) lred[w * 64 + qt * 32 + ql] = lsum[qt];
  }
  float* red = (float*)smem;                     // 32KB staging region
  if (wk_ == 1) {
    #pragma unroll
    for (int t = 0; t < 4; ++t) {
      f32x16 a = acc[t >> 1][t & 1];
      #pragma unroll
      for (int qd = 0; qd < 4; ++qd) {
        f32x4 v = { a[qd * 4], a[qd * 4 + 1], a[qd * 4 + 2], a[qd * 4 + 3] };
        *(f32x4*)(red + wq_ * 4096 + (t * 4 + qd) * 256 + l * 4) = v;
      }
    }
  }
  __syncthreads();
  if (wk_ == 0) {
    float inv[2];
    #pragma unroll
    for (int qt = 0; qt < 2; ++qt)
      inv[qt] = 1.0f / (lred[w * 64 + qt * 32 + ql] + lred[(w + 2) * 64 + qt * 32 + ql]);

    const int b = bh >> 2, h = bh & 3;
    #pragma unroll
    for (int dt = 0; dt < 2; ++dt)
      #pragma unroll
      for (int qt = 0; qt < 2; ++qt) {
        const int t = dt * 2 + qt;
        f32x16 a = acc[dt][qt];
        const int tokg = b * SEQ + q0 + wq_ * 64 + qt * 32 + ql;
        const size_t rowbase = (size_t)(tokg >> 4) * 4096 + (tokg & 15) * 8 + hi * 4;
        #pragma unroll
        for (int qd = 0; qd < 4; ++qd) {
          f32x4 v = *(const f32x4*)(red + wq_ * 4096 + (t * 4 + qd) * 256 + l * 4);
          // d = dt*32 + 8*qd + 4*hi + m ; kk_col = h*64 + d (tiled A-layout)
          f16x4 ov = { (f16_t)((a[qd * 4 + 0] + v[0]) * inv[qt]),
                       (f16_t)((a[qd * 4 + 1] + v[1]) * inv[qt]),
                       (f16_t)((a[qd * 4 + 2] + v[2]) * inv[qt]),
                       (f16_t)((a[qd * 4 + 3] + v[3]) * inv[qt]) };
          *(f16x4*)(o + rowbase + (size_t)(h * 8 + dt * 4 + qd) * 128) = ov;
        }
      }
  }
}

// ---------------------------------------------------------------------------
// output projection: C rows = out-dim (a = woT frag) so each thread holds
// 4 consecutive n of one token -> float4 / bf16x4 stores.
__global__ __launch_bounds__(256) void out_proj_kernel(
    const f16_t* __restrict__ aA, const f16_t* __restrict__ wT,
    const float* __restrict__ bo, void* __restrict__ outv,
    const void* __restrict__ wq_raw) {
  __shared__ int s_mode;
  if (threadIdx.x < 64) {
    int m = detect_mode((const uint32_t*)wq_raw);
    if (threadIdx.x == 0) s_mode = m;
  }
  __syncthreads();
  const int mode = s_mode;

  const int lane = threadIdx.x & 63;
  const int wv   = threadIdx.x >> 6;
  const int c    = lane & 15;
  const int g    = lane >> 4;
  const int m0   = blockIdx.y * 64 + wv * 16;    // out-dim rows (4 y-blocks)
  const int n0   = blockIdx.x * 64;              // token cols (256 x-blocks)

  const f16_t* abase = wT + (size_t)(m0 >> 4) * 4096 + c * 8;
  const f16_t* bbase = aA + (size_t)(n0 >> 4) * 4096 + c * 8;
  f32x4 acc[4] = {};

  #pragma unroll
  for (int ks = 0; ks < 8; ++ks) {
    const int kc = (ks * 4 + g) * 128;
    f16x8 aw = *(const f16x8*)(abase + kc);
    #pragma unroll
    for (int nt = 0; nt < 4; ++nt) {
      f16x8 ba = *(const f16x8*)(bbase + (size_t)nt * 4096 + kc);
      acc[nt] = MFMA_F16(aw, ba, acc[nt], 0, 0, 0);
    }
  }

  const int nb = m0 + g * 4;                     // 4 consecutive out-dims
  const f32x4 bias = *(const f32x4*)(bo + nb);
  #pragma unroll
  for (int nt = 0; nt < 4; ++nt) {
    const int tok = n0 + nt * 16 + c;
    const size_t idx = (size_t)tok * DIM + nb;
    f32x4 v = { acc[nt][0] + bias[0], acc[nt][1] + bias[1],
                acc[nt][2] + bias[2], acc[nt][3] + bias[3] };
    if (mode) {
      *(f32x4*)((float*)outv + idx) = v;
    } else {
      bf16x4 ov = { (bf16_t)v[0], (bf16_t)v[1], (bf16_t)v[2], (bf16_t)v[3] };
      *(bf16x4*)((bf16_t*)outv + idx) = ov;
    }
  }
}

// ---------------------------------------------------------------------------
extern "C" void kernel_launch(void* const* d_in, const int* in_sizes, int n_in,
                              void* d_out, int out_size, void* d_ws, size_t ws_size,
                              hipStream_t stream) {
  (void)in_sizes; (void)n_in; (void)out_size; (void)ws_size;
  const void* x  = d_in[0];
  const void* wq = d_in[1];
  const void* wk = d_in[2];
  const void* wv = d_in[3];
  const void* wo = d_in[4];
  const void* bo = d_in[5];

  f16_t* ws    = (f16_t*)d_ws;
  f16_t* xA    = ws + WS_XA;
  f16_t* q     = ws + WS_Q;
  f16_t* kk    = ws + WS_K;
  f16_t* vt    = ws + WS_VT;
  f16_t* wT    = ws + WS_W;
  f16_t* woT   = ws + WS_W + 196608;
  float* bof   = (float*)(ws + WS_BO);
  f16_t* oattA = ws + WS_OATT;                 // aliases xA (x dead by then)

  cvt_all_kernel   <<<dim3(2177),      256, 0, stream>>>(x, wq, wk, wv, wo, bo,
                                                         xA, wT, bof);
  proj_fused_kernel<<<dim3(256, 4),    256, 0, stream>>>(xA, wT, q, kk, vt);
  attn_kernel      <<<dim3(16, 32),    256, 0, stream>>>(q, kk, vt, oattA);
  out_proj_kernel  <<<dim3(256, 4),    256, 0, stream>>>(oattA, woT, bof, d_out, wq);
}

// Round 14
// 173.454 us; speedup vs baseline: 1.1254x; 1.0713x over previous
//
#include <hip/hip_runtime.h>
#include <hip/hip_bf16.h>
#include <stdint.h>

#define DIM    256
#define NH     4
#define HD     64
#define BATCH  4
#define SEQ    4096
#define NTOK   (BATCH*SEQ)

typedef __bf16    bf16_t;
typedef __bf16    bf16x4 __attribute__((ext_vector_type(4)));
typedef _Float16  f16_t;
typedef _Float16  f16x8  __attribute__((ext_vector_type(8)));
typedef _Float16  f16x4  __attribute__((ext_vector_type(4)));
typedef float     f32x4  __attribute__((ext_vector_type(4)));
typedef float     f32x16 __attribute__((ext_vector_type(16)));
typedef unsigned short u16x8 __attribute__((ext_vector_type(8)));
typedef unsigned int   u32;
typedef u32 u32x2 __attribute__((ext_vector_type(2)));
typedef u32 u32x4 __attribute__((ext_vector_type(4)));

#define MFMA_F16    __builtin_amdgcn_mfma_f32_16x16x32_f16
#define MFMA32_F16  __builtin_amdgcn_mfma_f32_32x32x16_f16

// HEAD_DIM^-0.5 * log2(e): fold softmax scale + exp->exp2 into q at projection time
#define QSCALE 0.18033688011112042f

// ws layout in f16 element units (oattA aliases xA — x dead after projections)
#define WS_XA    ((size_t)0)          /* x in tiled A-layout, 16384x256 */
#define WS_Q     ((size_t)4194304)
#define WS_K     ((size_t)8388608)
#define WS_VT    ((size_t)12582912)
#define WS_W     ((size_t)16777216)   /* 4 x 65536 tiled: wqT,wkT,wvT,woT */
#define WS_BO    ((size_t)17039360)   /* float[256] */
#define WS_OATT  WS_XA

// Tiled fragment layout: elem (row, k) -> ((row>>4)*32 + (k>>3))*128 + (row&15)*8 + (k&7)
__device__ __forceinline__ size_t tiled_idx(int row, int k) {
  return ((size_t)(row >> 4) * 32 + (k >> 3)) * 128 + (row & 15) * 8 + (k & 7);
}

// ---------------------------------------------------------------------------
// In-block dtype detect (0 = bf16 inputs, 1 = fp32 inputs)
__device__ __forceinline__ int detect_mode(const uint32_t* wq_u32) {
  uint32_t word = wq_u32[(threadIdx.x & 63) * 431 + 17];   // < 32768 dwords
  uint32_t b = (word >> 8) & 0x7fu;
  unsigned long long m = __ballot(b >= 0x38u && b <= 0x3fu);
  return (__popcll(m) >= 32) ? 0 : 1;
}

__device__ __forceinline__ f16x8 cvt_chunk(const void* src, size_t elem, int mode) {
  f16x8 r;
  if (mode) {
    const float* s = (const float*)src + elem;
    f32x4 f0 = *(const f32x4*)(s);
    f32x4 f1 = *(const f32x4*)(s + 4);
    #pragma unroll
    for (int j = 0; j < 4; ++j) { r[j] = (f16_t)f0[j]; r[j + 4] = (f16_t)f1[j]; }
  } else {
    u16x8 v = *(const u16x8*)((const unsigned short*)src + elem);
    #pragma unroll
    for (int j = 0; j < 8; ++j) r[j] = (f16_t)__uint_as_float(((unsigned)v[j]) << 16);
  }
  return r;
}

// pack two f32 -> one dword of 2 f16 (v_cvt_pkrtz_f16_f32)
__device__ __forceinline__ u32 pkh(float a, float b) {
  auto h = __builtin_amdgcn_cvt_pkrtz(a, b);   // __fp16 ext_vector_type(2)
  return __builtin_bit_cast(u32, h);
}

// (x,y) -> (concat(x.lo,y.lo), concat(x.hi,y.hi))  [lane halves]
__device__ __forceinline__ void swap32(u32& x, u32& y) {
#if __has_builtin(__builtin_amdgcn_permlane32_swap)
  u32x2 r = __builtin_amdgcn_permlane32_swap(x, y, false, false);
  x = r[0]; y = r[1];
#else
  u32 xp = __shfl_xor((int)x, 32), yp = __shfl_xor((int)y, 32);
  const bool h = (threadIdx.x & 32) != 0;
  u32 nx = h ? yp : x;
  u32 ny = h ? y  : xp;
  x = nx; y = ny;
#endif
}

// ---------------------------------------------------------------------------
// cvt_all: x (blocks 0..2047) and 4 weights (2048..2175) -> fp16 in the TILED
// fragment layout; bias (block 2176) -> f32. One 8-elem chunk per thread.
// (R12 lesson: inline x-conversion in proj makes the x reads uncoalesced at
// 512B lane stride + 4x y-redundant — the separate coalesced pass is faster.)
__global__ __launch_bounds__(256) void cvt_all_kernel(
    const void* __restrict__ x,
    const void* __restrict__ wq, const void* __restrict__ wk,
    const void* __restrict__ wv, const void* __restrict__ wo,
    const void* __restrict__ bo,
    f16_t* __restrict__ xA, f16_t* __restrict__ wT,
    float* __restrict__ bof) {
  __shared__ int s_mode;
  if (threadIdx.x < 64) {
    int m = detect_mode((const uint32_t*)wq);
    if (threadIdx.x == 0) s_mode = m;
  }
  __syncthreads();
  const int mode = s_mode;
  const int bid = blockIdx.x;

  if (bid < 2048) {                     // x: 524288 chunks
    int idx = bid * 256 + (int)threadIdx.x;
    int tok = idx >> 5, kc = idx & 31;
    f16x8 r = cvt_chunk(x, (size_t)tok * DIM + kc * 8, mode);
    *(f16x8*)(xA + tiled_idx(tok, kc * 8)) = r;
  } else if (bid < 2176) {              // weights: 4 x 8192 chunks
    int idx = (bid - 2048) * 256 + (int)threadIdx.x;
    int which = idx >> 13, local = idx & 8191;
    const void* src = (which == 0) ? wq : (which == 1) ? wk : (which == 2) ? wv : wo;
    int n = local >> 5, kc = local & 31;
    f16x8 r = cvt_chunk(src, (size_t)n * DIM + kc * 8, mode);
    *(f16x8*)(wT + (size_t)which * 65536 + tiled_idx(n, kc * 8)) = r;
  } else {
    int i = threadIdx.x;
    bof[i] = mode ? ((const float*)bo)[i] : (float)((const bf16_t*)bo)[i];
  }
}

// ---------------------------------------------------------------------------
// Fused single-pass QKV projection (R20-verified, 174.5 µs config). One
// kernel, grid (256,4): each xA fragment is loaded ONCE and feeds all three
// weights — the tiled layout's A-frag and B-frag load formulas are identical,
// so xf[nt] serves as B-operand for Q/K (C rows = out-dim -> vectorized
// q/K-image stores) and as A-operand for V (C rows = token -> vectorized
// V-image stores).
__global__ __launch_bounds__(256) void proj_fused_kernel(
    const f16_t* __restrict__ xA, const f16_t* __restrict__ wT,
    f16_t* __restrict__ q, f16_t* __restrict__ kk, f16_t* __restrict__ vt) {
  const int lane = threadIdx.x & 63;
  const int wvi  = threadIdx.x >> 6;
  const int c    = lane & 15;
  const int g    = lane >> 4;

  const int m0 = blockIdx.y * 64 + wvi * 16;   // out-dim rows (q,k) / vd cols (v)
  const int n0 = blockIdx.x * 64;              // token tile

  const f16_t* aq = wT + (size_t)(m0 >> 4) * 4096 + c * 8;              // wq
  const f16_t* ak = wT + 65536 + (size_t)(m0 >> 4) * 4096 + c * 8;      // wk
  const f16_t* av = wT + 131072 + (size_t)(m0 >> 4) * 4096 + c * 8;     // wv
  const f16_t* bx = xA + (size_t)(n0 >> 4) * 4096 + c * 8;

  f32x4 accq[4] = {}, acck[4] = {}, accv[4] = {};
  #pragma unroll
  for (int ks = 0; ks < 8; ++ks) {
    const int kc = (ks * 4 + g) * 128;
    f16x8 xf[4];
    #pragma unroll
    for (int nt = 0; nt < 4; ++nt)
      xf[nt] = *(const f16x8*)(bx + (size_t)nt * 4096 + kc);
    f16x8 wqf = *(const f16x8*)(aq + kc);
    f16x8 wkf = *(const f16x8*)(ak + kc);
    f16x8 wvf = *(const f16x8*)(av + kc);
    #pragma unroll
    for (int nt = 0; nt < 4; ++nt) {
      accq[nt] = MFMA_F16(wqf, xf[nt], accq[nt], 0, 0, 0);  // C[d rows][tok cols]
      acck[nt] = MFMA_F16(wkf, xf[nt], acck[nt], 0, 0, 0);  // C[d rows][tok cols]
      accv[nt] = MFMA_F16(xf[nt], wvf, accv[nt], 0, 0, 0);  // C[tok rows][vd cols]
    }
  }

  // ---- q epilogue: rows = out-dim (4 consecutive d), cols = tokens ----
  const int nb = m0 + g * 4;
  const int hq = nb >> 6, d0 = nb & 63;
  #pragma unroll
  for (int nt = 0; nt < 4; ++nt) {
    const int tok = n0 + nt * 16 + c;
    const int b = tok >> 12, s = tok & 4095;
    f16x4 ov = { (f16_t)(accq[nt][0] * QSCALE), (f16_t)(accq[nt][1] * QSCALE),
                 (f16_t)(accq[nt][2] * QSCALE), (f16_t)(accq[nt][3] * QSCALE) };
    *(f16x4*)(q + (size_t)((b * NH + hq) * SEQ + s) * HD + d0) = ov;
  }

  // ---- K frag-image epilogue: [bh][kt64][h2][sg][hi2][row(32)][8] ----
  {
    const int sg = d0 >> 4, hi2 = (d0 >> 3) & 1, j0 = d0 & 7;
    #pragma unroll
    for (int nt = 0; nt < 4; ++nt) {
      const int tok = n0 + nt * 16 + c;
      const int b = tok >> 12, s = tok & 4095;
      const int kt = s >> 6, h2 = (s >> 5) & 1, row = s & 31;
      f16x4 ov = { (f16_t)acck[nt][0], (f16_t)acck[nt][1],
                   (f16_t)acck[nt][2], (f16_t)acck[nt][3] };
      *(f16x4*)(kk + (size_t)(b * NH + hq) * (SEQ * HD) + (size_t)kt * 4096 +
                h2 * 2048 + sg * 512 + hi2 * 256 + row * 8 + j0) = ov;
    }
  }

  // ---- V frag-image epilogue: rows = tokens (4 consecutive jv), cols = vd ----
  #pragma unroll
  for (int nt = 0; nt < 4; ++nt) {
    const int tok0 = n0 + nt * 16 + g * 4;       // 4 consecutive tokens
    const int b = tok0 >> 12, s0 = tok0 & 4095;
    const int kt = s0 >> 6, kin0 = s0 & 63;
    const int h2 = kin0 >> 5, kb = (kin0 >> 4) & 1, hiv = (kin0 >> 3) & 1, jv0 = kin0 & 7;
    const int vd = m0 + c;
    const int h = vd >> 6, d = vd & 63;
    f16x4 ov = { (f16_t)accv[nt][0], (f16_t)accv[nt][1],
                 (f16_t)accv[nt][2], (f16_t)accv[nt][3] };
    *(f16x4*)(vt + (size_t)(b * NH + h) * (SEQ * HD) + (size_t)kt * 4096 +
              h2 * 2048 + (d >> 5) * 1024 + kb * 512 + hiv * 256 +
              (d & 31) * 8 + jv0) = ov;
  }
}

// ---------------------------------------------------------------------------
// Flash attention — R8-verified frag-streaming kernel (77.6 µs, 0 bank
// conflicts), kept verbatim; NO setprio (R13 measured it −9 µs here: with
// 2 free-running waves/SIMD there's no phase diversity to arbitrate, and the
// setprio pairs fence the compiler's exp2/MFMA interleave).
// 2 waves/SIMD is the hard cap: the wave holds ~180 unified regs (116 VGPR +
// 64 AGPR acc); HW occupancy steps at 64/128/256 regs ⇒ exactly 2 waves/SIMD.
__global__ __launch_bounds__(256, 2) void attn_kernel(
    const f16_t* __restrict__ q, const f16_t* __restrict__ kimg,
    const f16_t* __restrict__ vimg, f16_t* __restrict__ o) {
  __shared__ __align__(16) f16_t smem[16896];   // epilogue: 32KB red + 1KB lred

  const int tid = threadIdx.x;
  const int l   = tid & 63;
  const int w   = tid >> 6;
  const int wq_ = w & 1;           // q half: 64 queries
  const int wk_ = w >> 1;          // k half of each 64-key tile: 32 keys
  const int ql  = l & 31;
  const int hi  = l >> 5;
  const int bh  = blockIdx.x;      // XCD-locality: id%8 == bh%8
  const int q0  = blockIdx.y * 128;

  // Q B-frags (32x32x16: col=l&31, k=hi*8+j): qf[qt][s] over d = s*16+hi*8..+8
  const f16_t* qb = q + ((size_t)bh * SEQ + q0 + wq_ * 64 + ql) * HD + hi * 8;
  f16x8 qf[2][4];
  #pragma unroll
  for (int qt = 0; qt < 2; ++qt)
    #pragma unroll
    for (int s = 0; s < 4; ++s)
      qf[qt][s] = *(const f16x8*)(qb + (size_t)qt * 32 * HD + s * 16);

  // per-wave fragment base pointers into the frag-images (f16 units)
  const f16_t* kW = kimg + (size_t)bh * (SEQ * HD) + wk_ * 2048 + l * 8;
  const f16_t* vW = vimg + (size_t)bh * (SEQ * HD) + wk_ * 2048 + l * 8;

  f32x16 acc[2][2] = {};           // [dt][qt]: O^T[d=dt*32+crow][q=qt*32+ql]
  float lsum[2] = {0.f, 0.f};

  f16x8 kfA[4], vfA[2][2], kfB[4], vfB[2][2];

  // load tile 0 into A
  #pragma unroll
  for (int s = 0; s < 4; ++s) kfA[s] = *(const f16x8*)(kW + s * 512);
  #pragma unroll
  for (int dt = 0; dt < 2; ++dt)
    #pragma unroll
    for (int kb = 0; kb < 2; ++kb)
      vfA[dt][kb] = *(const f16x8*)(vW + dt * 1024 + kb * 512);

  auto body = [&](f16x8 (&kf)[4], f16x8 (&vf)[2][2],
                  f16x8 (&kfn)[4], f16x8 (&vfn)[2][2], int kt) {
    if (kt < SEQ / 64 - 1) {                 // prefetch tile kt+1 -> other regs
      const f16_t* kP = kW + (size_t)(kt + 1) * 4096;
      const f16_t* vP = vW + (size_t)(kt + 1) * 4096;
      #pragma unroll
      for (int s = 0; s < 4; ++s) kfn[s] = *(const f16x8*)(kP + s * 512);
      #pragma unroll
      for (int dt = 0; dt < 2; ++dt)
        #pragma unroll
        for (int kb = 0; kb < 2; ++kb)
          vfn[dt][kb] = *(const f16x8*)(vP + dt * 1024 + kb * 512);
    }
    #pragma unroll
    for (int qt = 0; qt < 2; ++qt) {
      f32x16 st = {};
      #pragma unroll
      for (int s = 0; s < 4; ++s) st = MFMA32_F16(kf[s], qf[qt][s], st, 0, 0, 0);
      float p[16];
      #pragma unroll
      for (int r = 0; r < 16; ++r) p[r] = __builtin_amdgcn_exp2f(st[r]);
      float ls = 0.f;
      #pragma unroll
      for (int r = 0; r < 16; r += 4) ls += (p[r] + p[r + 1]) + (p[r + 2] + p[r + 3]);
      lsum[qt] += ls;
      f16x8 pf0, pf1;
      {
        u32 d0 = pkh(p[0], p[1]), d1 = pkh(p[2], p[3]);
        u32 d2 = pkh(p[4], p[5]), d3 = pkh(p[6], p[7]);
        swap32(d0, d2); swap32(d1, d3);
        u32x4 fd; fd[0] = d0; fd[1] = d1; fd[2] = d2; fd[3] = d3;
        pf0 = __builtin_bit_cast(f16x8, fd);
      }
      {
        u32 d0 = pkh(p[8], p[9]),  d1 = pkh(p[10], p[11]);
        u32 d2 = pkh(p[12], p[13]), d3 = pkh(p[14], p[15]);
        swap32(d0, d2); swap32(d1, d3);
        u32x4 fd; fd[0] = d0; fd[1] = d1; fd[2] = d2; fd[3] = d3;
        pf1 = __builtin_bit_cast(f16x8, fd);
      }
      #pragma unroll
      for (int dt = 0; dt < 2; ++dt) {
        f32x16 a = acc[dt][qt];
        a = MFMA32_F16(vf[dt][0], pf0, a, 0, 0, 0);
        a = MFMA32_F16(vf[dt][1], pf1, a, 0, 0, 0);
        acc[dt][qt] = a;
      }
    }
  };

  for (int kt = 0; kt < SEQ / 64; kt += 2) {
    body(kfA, vfA, kfB, vfB, kt);
    body(kfB, vfB, kfA, vfA, kt + 1);
  }

  // ---- reductions: l across hi halves + wk pair; O^T 2-way via LDS ----
  float* lred = (float*)(smem + 16384);          // byte 32768: 256 floats
  #pragma unroll
  for (int qt = 0; qt < 2; ++qt) {
    lsum[qt] += __shfl_xor(lsum[qt], 32);
    if (hi == 0) lred[w * 64 + qt * 32 + ql] = lsum[qt];
  }
  float* red = (float*)smem;                     // 32KB staging region
  if (wk_ == 1) {
    #pragma unroll
    for (int t = 0; t < 4; ++t) {
      f32x16 a = acc[t >> 1][t & 1];
      #pragma unroll
      for (int qd = 0; qd < 4; ++qd) {
        f32x4 v = { a[qd * 4], a[qd * 4 + 1], a[qd * 4 + 2], a[qd * 4 + 3] };
        *(f32x4*)(red + wq_ * 4096 + (t * 4 + qd) * 256 + l * 4) = v;
      }
    }
  }
  __syncthreads();
  if (wk_ == 0) {
    float inv[2];
    #pragma unroll
    for (int qt = 0; qt < 2; ++qt)
      inv[qt] = 1.0f / (lred[w * 64 + qt * 32 + ql] + lred[(w + 2) * 64 + qt * 32 + ql]);

    const int b = bh >> 2, h = bh & 3;
    #pragma unroll
    for (int dt = 0; dt < 2; ++dt)
      #pragma unroll
      for (int qt = 0; qt < 2; ++qt) {
        const int t = dt * 2 + qt;
        f32x16 a = acc[dt][qt];
        const int tokg = b * SEQ + q0 + wq_ * 64 + qt * 32 + ql;
        const size_t rowbase = (size_t)(tokg >> 4) * 4096 + (tokg & 15) * 8 + hi * 4;
        #pragma unroll
        for (int qd = 0; qd < 4; ++qd) {
          f32x4 v = *(const f32x4*)(red + wq_ * 4096 + (t * 4 + qd) * 256 + l * 4);
          // d = dt*32 + 8*qd + 4*hi + m ; kk_col = h*64 + d (tiled A-layout)
          f16x4 ov = { (f16_t)((a[qd * 4 + 0] + v[0]) * inv[qt]),
                       (f16_t)((a[qd * 4 + 1] + v[1]) * inv[qt]),
                       (f16_t)((a[qd * 4 + 2] + v[2]) * inv[qt]),
                       (f16_t)((a[qd * 4 + 3] + v[3]) * inv[qt]) };
          *(f16x4*)(o + rowbase + (size_t)(h * 8 + dt * 4 + qd) * 128) = ov;
        }
      }
  }
}

// ---------------------------------------------------------------------------
// output projection: C rows = out-dim (a = woT frag) so each thread holds
// 4 consecutive n of one token -> float4 / bf16x4 stores.
__global__ __launch_bounds__(256) void out_proj_kernel(
    const f16_t* __restrict__ aA, const f16_t* __restrict__ wT,
    const float* __restrict__ bo, void* __restrict__ outv,
    const void* __restrict__ wq_raw) {
  __shared__ int s_mode;
  if (threadIdx.x < 64) {
    int m = detect_mode((const uint32_t*)wq_raw);
    if (threadIdx.x == 0) s_mode = m;
  }
  __syncthreads();
  const int mode = s_mode;

  const int lane = threadIdx.x & 63;
  const int wv   = threadIdx.x >> 6;
  const int c    = lane & 15;
  const int g    = lane >> 4;
  const int m0   = blockIdx.y * 64 + wv * 16;    // out-dim rows (4 y-blocks)
  const int n0   = blockIdx.x * 64;              // token cols (256 x-blocks)

  const f16_t* abase = wT + (size_t)(m0 >> 4) * 4096 + c * 8;
  const f16_t* bbase = aA + (size_t)(n0 >> 4) * 4096 + c * 8;
  f32x4 acc[4] = {};

  #pragma unroll
  for (int ks = 0; ks < 8; ++ks) {
    const int kc = (ks * 4 + g) * 128;
    f16x8 aw = *(const f16x8*)(abase + kc);
    #pragma unroll
    for (int nt = 0; nt < 4; ++nt) {
      f16x8 ba = *(const f16x8*)(bbase + (size_t)nt * 4096 + kc);
      acc[nt] = MFMA_F16(aw, ba, acc[nt], 0, 0, 0);
    }
  }

  const int nb = m0 + g * 4;                     // 4 consecutive out-dims
  const f32x4 bias = *(const f32x4*)(bo + nb);
  #pragma unroll
  for (int nt = 0; nt < 4; ++nt) {
    const int tok = n0 + nt * 16 + c;
    const size_t idx = (size_t)tok * DIM + nb;
    f32x4 v = { acc[nt][0] + bias[0], acc[nt][1] + bias[1],
                acc[nt][2] + bias[2], acc[nt][3] + bias[3] };
    if (mode) {
      *(f32x4*)((float*)outv + idx) = v;
    } else {
      bf16x4 ov = { (bf16_t)v[0], (bf16_t)v[1], (bf16_t)v[2], (bf16_t)v[3] };
      *(bf16x4*)((bf16_t*)outv + idx) = ov;
    }
  }
}

// ---------------------------------------------------------------------------
extern "C" void kernel_launch(void* const* d_in, const int* in_sizes, int n_in,
                              void* d_out, int out_size, void* d_ws, size_t ws_size,
                              hipStream_t stream) {
  (void)in_sizes; (void)n_in; (void)out_size; (void)ws_size;
  const void* x  = d_in[0];
  const void* wq = d_in[1];
  const void* wk = d_in[2];
  const void* wv = d_in[3];
  const void* wo = d_in[4];
  const void* bo = d_in[5];

  f16_t* ws    = (f16_t*)d_ws;
  f16_t* xA    = ws + WS_XA;
  f16_t* q     = ws + WS_Q;
  f16_t* kk    = ws + WS_K;
  f16_t* vt    = ws + WS_VT;
  f16_t* wT    = ws + WS_W;
  f16_t* woT   = ws + WS_W + 196608;
  float* bof   = (float*)(ws + WS_BO);
  f16_t* oattA = ws + WS_OATT;                 // aliases xA (x dead by then)

  cvt_all_kernel   <<<dim3(2177),      256, 0, stream>>>(x, wq, wk, wv, wo, bo,
                                                         xA, wT, bof);
  proj_fused_kernel<<<dim3(256, 4),    256, 0, stream>>>(xA, wT, q, kk, vt);
  attn_kernel      <<<dim3(16, 32),    256, 0, stream>>>(q, kk, vt, oattA);
  out_proj_kernel  <<<dim3(256, 4),    256, 0, stream>>>(oattA, woT, bof, d_out, wq);
}